// Round 4
// baseline (71.750 us; speedup 1.0000x reference)
//
#include <hip/hip_runtime.h>
#include <hip/hip_bf16.h>
#include <cmath>

// Problem constants (from reference setup_inputs)
#define BB 64
#define LL 512
#define NN 64
#define AA 64
#define PP 16
#define DD 256
#define MAX_OFF 4.0f
#define STRIDE_S 8

typedef __attribute__((ext_vector_type(8))) short short8_t;   // 8 bf16 = 4 VGPR
typedef __attribute__((ext_vector_type(4))) float float4_t;   // MFMA C/D

// fp32 -> bf16 round-to-nearest-even (finite inputs)
static __device__ __forceinline__ unsigned f2bf(float x) {
    union { float f; unsigned u; } v; v.f = x;
    return (v.u + 0x7FFFu + ((v.u >> 16) & 1u)) >> 16;
}

// ---------------------------------------------------------------------------
// Kernel 1: conv1d(N->32, k=3, zero pad 1) + ReLU + partial sum over l-chunk.
// grid = (8 chunks, B). block = 256 (o = t&31, lgroup = t>>5, 8 l each).
// ---------------------------------------------------------------------------
__global__ __launch_bounds__(256) void conv_pool_kernel(
    const float* __restrict__ x,        // (B, L, N)
    const float* __restrict__ conv_w,   // (32, N, 3)
    const float* __restrict__ conv_b,   // (32)
    float* __restrict__ pool_partial)   // (B, 8, 32)
{
    const int c = blockIdx.x;   // l-chunk (64 wide)
    const int b = blockIdx.y;
    const int t = threadIdx.x;

    __shared__ float4 wl[3 * 16 * 32];   // [k][nv][o] as float4 over n
    __shared__ float  xl[66 * 64];       // rows c*64-1 .. c*64+64, stride 64
    __shared__ float  red[8][32];

    // stage weights transposed: wl[(k*16+nv)*32 + o] = conv_w[o][nv*4+0..3][k]
    for (int idx = t; idx < 1536; idx += 256) {
        int o  = idx & 31;
        int nv = (idx >> 5) & 15;
        int k  = idx >> 9;
        float4 v;
        v.x = conv_w[(o * 64 + nv * 4 + 0) * 3 + k];
        v.y = conv_w[(o * 64 + nv * 4 + 1) * 3 + k];
        v.z = conv_w[(o * 64 + nv * 4 + 2) * 3 + k];
        v.w = conv_w[(o * 64 + nv * 4 + 3) * 3 + k];
        wl[idx] = v;
    }

    // stage x rows (zero padding outside [0, L))
    const int base_row = c * 64 - 1;
    for (int idx = t; idx < 66 * 16; idx += 256) {
        int j  = idx >> 4;
        int nv = idx & 15;
        int row = base_row + j;
        float4 v = make_float4(0.f, 0.f, 0.f, 0.f);
        if (row >= 0 && row < LL)
            v = *reinterpret_cast<const float4*>(&x[((size_t)b * LL + row) * NN + nv * 4]);
        *reinterpret_cast<float4*>(&xl[j * 64 + nv * 4]) = v;
    }
    __syncthreads();

    const int o  = t & 31;
    const int lg = t >> 5;    // 0..7  -> local l = lg*8 .. lg*8+7

    float s[8];
#pragma unroll
    for (int j = 0; j < 8; ++j) s[j] = 0.f;

#pragma unroll
    for (int nv = 0; nv < 16; ++nv) {
        float4 xv[10];
#pragma unroll
        for (int j = 0; j < 10; ++j)
            xv[j] = *reinterpret_cast<const float4*>(&xl[(lg * 8 + j) * 64 + nv * 4]);
#pragma unroll
        for (int k = 0; k < 3; ++k) {
            float4 w4 = wl[(k * 16 + nv) * 32 + o];
#pragma unroll
            for (int j = 0; j < 8; ++j) {
                s[j] = fmaf(xv[j + k].x, w4.x, s[j]);
                s[j] = fmaf(xv[j + k].y, w4.y, s[j]);
                s[j] = fmaf(xv[j + k].z, w4.z, s[j]);
                s[j] = fmaf(xv[j + k].w, w4.w, s[j]);
            }
        }
    }

    const float cb = conv_b[o];
    float part = 0.f;
#pragma unroll
    for (int j = 0; j < 8; ++j) part += fmaxf(s[j] + cb, 0.f);
    red[lg][o] = part;
    __syncthreads();

    if (t < 32) {
        float sum = 0.f;
#pragma unroll
        for (int g = 0; g < 8; ++g) sum += red[g][t];
        pool_partial[((size_t)b * 8 + c) * 32 + t] = sum;
    }
}

// ---------------------------------------------------------------------------
// Kernel 2: fused {pool-reduce + linear + tanh} + bilinear gather + MFMA
// patch projection, AGRP=4 anchors per block.
// grid = (A/AGRP, B) = (16, 64) = 1024 blocks, block = 256 (4 waves).
// Staged row range [8*a0-12, 8*a0+36] is delta-INDEPENDENT (|delta|<=4),
// so x staging overlaps the pooled/delta computation.
// MFMA: A = wp (M=d), B = samp (N=n), K=16 padded to 32 (A k>=16 zero).
// C layout row=d -> thread's 4 acc regs are 4 consecutive d's -> dwordx4.
// ---------------------------------------------------------------------------
#define AGRP 4
#define XROWS 49       // 8*(AGRP-1) + 24 + 17
#define XR_STRIDE 68   // f32 words; 68%32==4 -> <=2-way bank aliasing (free)
#define SA_ST 24       // bf16 per samp row (16 data + 8 pad); rows 16B-aligned

__global__ __launch_bounds__(256) void patch_proj_kernel(
    const float* __restrict__ x,            // (B, L, N)
    const float* __restrict__ wp_w,         // (D, P)
    const float* __restrict__ wp_b,         // (D)
    const float* __restrict__ pool_partial, // (B, 8, 32)
    const float* __restrict__ lin_w,        // (A, 32)
    const float* __restrict__ lin_b,        // (A)
    float* __restrict__ out)                // (B*N, A, D)
{
    const int a0 = blockIdx.x * AGRP;
    const int b  = blockIdx.y;
    const int t  = threadIdx.x;
    const int lane = t & 63;
    const int w  = t >> 6;      // wave id 0..3 -> d base w*64
    const int lg = lane >> 4;   // k-block for fragments; C row group
    const int lr = lane & 15;   // A row (=d) / B col (=n)

    __shared__ float          xr[XROWS * XR_STRIDE];
    __shared__ unsigned short sampA[AGRP * 64 * SA_ST];   // [a][n][p] bf16
    __shared__ float          pooled[32];
    __shared__ float          bases[AGRP];

    const int r_lo = a0 * 8 - 12;

    // ---- stage XROWS rows of x[b] (clamped; clamped rows only read via
    //      clamped i0/i1, so values match exactly) ----
    for (int idx = t; idx < XROWS * 16; idx += 256) {
        int j  = idx >> 4;
        int nv = idx & 15;
        int row = max(0, min(LL - 1, r_lo + j));
        float4 v = *reinterpret_cast<const float4*>(&x[((size_t)b * LL + row) * NN + nv * 4]);
        *reinterpret_cast<float4*>(&xr[j * XR_STRIDE + nv * 4]) = v;
    }
    // ---- pooled mean (overlaps staging) ----
    if (t < 32) {
        float s = 0.f;
#pragma unroll
        for (int c = 0; c < 8; ++c) s += pool_partial[((size_t)b * 8 + c) * 32 + t];
        pooled[t] = s * (1.0f / 512.0f);
    }
    __syncthreads();

    // ---- delta -> sampling base, one thread per a ----
    if (t < AGRP) {
        const int a = a0 + t;
        float s = lin_b[a];
#pragma unroll
        for (int o = 0; o < 32; ++o) s = fmaf(pooled[o], lin_w[a * 32 + o], s);
        bases[t] = (float)(a * STRIDE_S) - 7.5f + MAX_OFF * tanhf(s);
    }
    __syncthreads();

    // ---- bilinear -> bf16 sampA for each a ----
    {
        const int pp  = t & 7;    // p-pair: p = 2*pp, 2*pp+1
        const int nr0 = t >> 3;   // 0..31
#pragma unroll
        for (int al = 0; al < AGRP; ++al) {
            const float base = bases[al];
            float f_[2]; int j0_[2], j1_[2];
#pragma unroll
            for (int q = 0; q < 2; ++q) {
                int p = pp * 2 + q;
                float xs = base + (float)p;
                xs = fminf(fmaxf(xs, 0.f), (float)(LL - 1));
                int i0 = (int)floorf(xs);
                f_[q]  = xs - (float)i0;
                j0_[q] = i0 - r_lo;                    // in [0, XROWS-1]
                j1_[q] = min(i0 + 1, LL - 1) - r_lo;   // in [0, XROWS-1]
            }
#pragma unroll
            for (int h = 0; h < 2; ++h) {
                int n = nr0 + 32 * h;
                unsigned pk = 0;
#pragma unroll
                for (int q = 0; q < 2; ++q) {
                    float g0 = xr[j0_[q] * XR_STRIDE + n];
                    float g1 = xr[j1_[q] * XR_STRIDE + n];
                    float s  = g0 + f_[q] * (g1 - g0);
                    pk |= f2bf(s) << (16 * q);
                }
                *reinterpret_cast<unsigned*>(&sampA[(al * 64 + n) * SA_ST + pp * 2]) = pk;
            }
        }
    }

    // ---- A fragments (wp fp32 -> bf16 in-register; k-blocks lg>=2 zero) ----
    short8_t afrag[4];
    float4   bias4[4];
    const short8_t zero8 = {0, 0, 0, 0, 0, 0, 0, 0};
#pragma unroll
    for (int i = 0; i < 4; ++i) {
        const int d = w * 64 + i * 16 + lr;
        short8_t v = zero8;
        if (lg < 2) {
            float4 w0 = *reinterpret_cast<const float4*>(&wp_w[d * 16 + lg * 8 + 0]);
            float4 w1 = *reinterpret_cast<const float4*>(&wp_w[d * 16 + lg * 8 + 4]);
            unsigned p0 = f2bf(w0.x) | (f2bf(w0.y) << 16);
            unsigned p1 = f2bf(w0.z) | (f2bf(w0.w) << 16);
            unsigned p2 = f2bf(w1.x) | (f2bf(w1.y) << 16);
            unsigned p3 = f2bf(w1.z) | (f2bf(w1.w) << 16);
            v[0] = (short)(p0 & 0xFFFF); v[1] = (short)(p0 >> 16);
            v[2] = (short)(p1 & 0xFFFF); v[3] = (short)(p1 >> 16);
            v[4] = (short)(p2 & 0xFFFF); v[5] = (short)(p2 >> 16);
            v[6] = (short)(p3 & 0xFFFF); v[7] = (short)(p3 >> 16);
        }
        afrag[i] = v;
        bias4[i] = *reinterpret_cast<const float4*>(&wp_b[w * 64 + i * 16 + lg * 4]);
    }
    __syncthreads();

    // ---- per a: B fragments, 16 MFMAs, direct dwordx4 stores ----
    const size_t ob0 = (((size_t)b * NN) * AA + a0) * DD + w * 64 + lg * 4;
#pragma unroll
    for (int al = 0; al < AGRP; ++al) {
        short8_t bfrag[4];
#pragma unroll
        for (int s = 0; s < 4; ++s)
            bfrag[s] = *reinterpret_cast<const short8_t*>(
                &sampA[(al * 64 + s * 16 + lr) * SA_ST + (lg & 1) * 8]);

        float4_t acc[4][4];   // [n-strip s][d-tile i]
#pragma unroll
        for (int i = 0; i < 4; ++i) {
            float4_t c4 = {bias4[i].x, bias4[i].y, bias4[i].z, bias4[i].w};
#pragma unroll
            for (int s = 0; s < 4; ++s) acc[s][i] = c4;
        }
#pragma unroll
        for (int s = 0; s < 4; ++s)
#pragma unroll
            for (int i = 0; i < 4; ++i)
                acc[s][i] = __builtin_amdgcn_mfma_f32_16x16x32_bf16(
                    afrag[i], bfrag[s], acc[s][i], 0, 0, 0);

        const size_t ob = ob0 + (size_t)al * DD;
#pragma unroll
        for (int s = 0; s < 4; ++s) {
            const int n = s * 16 + lr;
            const size_t rb = ob + (size_t)n * (AA * DD);
#pragma unroll
            for (int i = 0; i < 4; ++i)
                *reinterpret_cast<float4_t*>(&out[rb + i * 16]) = acc[s][i];
        }
    }
}

// ---------------------------------------------------------------------------
extern "C" void kernel_launch(void* const* d_in, const int* in_sizes, int n_in,
                              void* d_out, int out_size, void* d_ws, size_t ws_size,
                              hipStream_t stream)
{
    const float* x      = (const float*)d_in[0];
    const float* conv_w = (const float*)d_in[1];
    const float* conv_b = (const float*)d_in[2];
    const float* lin_w  = (const float*)d_in[3];
    const float* lin_b  = (const float*)d_in[4];
    const float* wp_w   = (const float*)d_in[5];
    const float* wp_b   = (const float*)d_in[6];
    float* out = (float*)d_out;

    float* pool_partial = (float*)d_ws;   // 64*8*32 = 16384 floats

    conv_pool_kernel<<<dim3(8, BB), 256, 0, stream>>>(x, conv_w, conv_b, pool_partial);
    patch_proj_kernel<<<dim3(AA / AGRP, BB), 256, 0, stream>>>(
        x, wp_w, wp_b, pool_partial, lin_w, lin_b, out);
}

// Round 5
// 65.533 us; speedup vs baseline: 1.0949x; 1.0949x over previous
//
#include <hip/hip_runtime.h>
#include <hip/hip_bf16.h>
#include <cmath>

// Problem constants (from reference setup_inputs)
#define BB 64
#define LL 512
#define NN 64
#define AA 64
#define PP 16
#define DD 256
#define MAX_OFF 4.0f
#define STRIDE_S 8

typedef __attribute__((ext_vector_type(8))) short short8_t;   // 8 bf16 = 4 VGPR
typedef __attribute__((ext_vector_type(4))) float float4_t;   // MFMA C/D

// fp32 -> bf16 round-to-nearest-even (finite inputs)
static __device__ __forceinline__ unsigned f2bf(float x) {
    union { float f; unsigned u; } v; v.f = x;
    return (v.u + 0x7FFFu + ((v.u >> 16) & 1u)) >> 16;
}

// ---------------------------------------------------------------------------
// Kernel 1a: conv1d(N->32, k=3, zero pad 1) + ReLU + partial sum over l-chunk.
// grid = (8 chunks, B). block = 256 (o = t&31, lgroup = t>>5, 8 l each).
// ---------------------------------------------------------------------------
__global__ __launch_bounds__(256) void conv_pool_kernel(
    const float* __restrict__ x,        // (B, L, N)
    const float* __restrict__ conv_w,   // (32, N, 3)
    const float* __restrict__ conv_b,   // (32)
    float* __restrict__ pool_partial)   // (B, 8, 32)
{
    const int c = blockIdx.x;   // l-chunk (64 wide)
    const int b = blockIdx.y;
    const int t = threadIdx.x;

    __shared__ float4 wl[3 * 16 * 32];   // [k][nv][o] as float4 over n
    __shared__ float  xl[66 * 64];       // rows c*64-1 .. c*64+64, stride 64
    __shared__ float  red[8][32];

    // stage weights transposed: wl[(k*16+nv)*32 + o] = conv_w[o][nv*4+0..3][k]
    for (int idx = t; idx < 1536; idx += 256) {
        int o  = idx & 31;
        int nv = (idx >> 5) & 15;
        int k  = idx >> 9;
        float4 v;
        v.x = conv_w[(o * 64 + nv * 4 + 0) * 3 + k];
        v.y = conv_w[(o * 64 + nv * 4 + 1) * 3 + k];
        v.z = conv_w[(o * 64 + nv * 4 + 2) * 3 + k];
        v.w = conv_w[(o * 64 + nv * 4 + 3) * 3 + k];
        wl[idx] = v;
    }

    // stage x rows (zero padding outside [0, L))
    const int base_row = c * 64 - 1;
    for (int idx = t; idx < 66 * 16; idx += 256) {
        int j  = idx >> 4;
        int nv = idx & 15;
        int row = base_row + j;
        float4 v = make_float4(0.f, 0.f, 0.f, 0.f);
        if (row >= 0 && row < LL)
            v = *reinterpret_cast<const float4*>(&x[((size_t)b * LL + row) * NN + nv * 4]);
        *reinterpret_cast<float4*>(&xl[j * 64 + nv * 4]) = v;
    }
    __syncthreads();

    const int o  = t & 31;
    const int lg = t >> 5;    // 0..7  -> local l = lg*8 .. lg*8+7

    float s[8];
#pragma unroll
    for (int j = 0; j < 8; ++j) s[j] = 0.f;

#pragma unroll
    for (int nv = 0; nv < 16; ++nv) {
        float4 xv[10];
#pragma unroll
        for (int j = 0; j < 10; ++j)
            xv[j] = *reinterpret_cast<const float4*>(&xl[(lg * 8 + j) * 64 + nv * 4]);
#pragma unroll
        for (int k = 0; k < 3; ++k) {
            float4 w4 = wl[(k * 16 + nv) * 32 + o];
#pragma unroll
            for (int j = 0; j < 8; ++j) {
                s[j] = fmaf(xv[j + k].x, w4.x, s[j]);
                s[j] = fmaf(xv[j + k].y, w4.y, s[j]);
                s[j] = fmaf(xv[j + k].z, w4.z, s[j]);
                s[j] = fmaf(xv[j + k].w, w4.w, s[j]);
            }
        }
    }

    const float cb = conv_b[o];
    float part = 0.f;
#pragma unroll
    for (int j = 0; j < 8; ++j) part += fmaxf(s[j] + cb, 0.f);
    red[lg][o] = part;
    __syncthreads();

    if (t < 32) {
        float sum = 0.f;
#pragma unroll
        for (int g = 0; g < 8; ++g) sum += red[g][t];
        pool_partial[((size_t)b * 8 + c) * 32 + t] = sum;
    }
}

// ---------------------------------------------------------------------------
// Kernel 1b: reduce partials -> pooled mean -> linear(32->A) -> 4*tanh.
// grid = B, block = 64 (one thread per a).
// ---------------------------------------------------------------------------
__global__ __launch_bounds__(64) void delta_kernel(
    const float* __restrict__ pool_partial, // (B, 8, 32)
    const float* __restrict__ lin_w,        // (A, 32)
    const float* __restrict__ lin_b,        // (A)
    float* __restrict__ delta)              // (B, A)
{
    const int b = blockIdx.x;
    const int t = threadIdx.x;
    __shared__ float pooled[32];

    if (t < 32) {
        float s = 0.f;
#pragma unroll
        for (int c = 0; c < 8; ++c) s += pool_partial[((size_t)b * 8 + c) * 32 + t];
        pooled[t] = s * (1.0f / 512.0f);
    }
    __syncthreads();

    float s = lin_b[t];
#pragma unroll
    for (int o = 0; o < 32; ++o) s = fmaf(pooled[o], lin_w[t * 32 + o], s);
    delta[b * AA + t] = MAX_OFF * tanhf(s);
}

// ---------------------------------------------------------------------------
// Kernel 2: bilinear gather + MFMA patch projection + wave-local LDS epilogue.
// grid = (A, B) = 4096 blocks, block = 256 (4 waves).
// MFMA: A = wp (M=d), B = samp (N=n), K=16 padded to 32 (A k>=16 zero).
// Epilogue: each wave redistributes its C slice through a PRIVATE 4.3 KB LDS
// region (wave-synchronous, no barriers) so every global store instruction
// writes 4 x 256 B contiguous segments (nontemporal dwordx4).
// ---------------------------------------------------------------------------
#define XR_STRIDE 68   // f32 words; 68%32==4 -> <=2-way bank aliasing (free)
#define SA_ST     24   // bf16 per samp row (16 data + 8 pad); rows 16B-aligned
#define CW_ST     68   // f32 words per cst row (64 + 4 pad); 16B-aligned

__global__ __launch_bounds__(256) void patch_proj_kernel(
    const float* __restrict__ x,            // (B, L, N)
    const unsigned short* __restrict__ wp16,// (D, P) bf16
    const float* __restrict__ wp_b,         // (D)
    const float* __restrict__ delta,        // (B, A)
    float* __restrict__ out)                // (B*N, A, D)
{
    const int a = blockIdx.x;
    const int b = blockIdx.y;
    const int t = threadIdx.x;
    const int lane = t & 63;
    const int w  = t >> 6;      // wave id 0..3 -> d base w*64
    const int lg = lane >> 4;   // k-block for A/B fragments; C row group
    const int lr = lane & 15;   // A row (=d) / B col (=n)

    __shared__ float          xr[17 * XR_STRIDE];   // 17 rows of x[b]
    __shared__ unsigned short sampA[64 * SA_ST];    // [n][p] bf16
    __shared__ float          cst[4 * 16 * CW_ST];  // per-wave C transpose slice

    const float dlt  = delta[b * AA + a];
    const float base = (float)(a * STRIDE_S) - 7.5f + dlt;   // + p gives xs
    const int   r0   = (int)floorf(base);

    // ---- stage 17 rows of x[b] (clamped rows only read via clamped i0/i1) ----
    for (int idx = t; idx < 17 * 16; idx += 256) {
        int j  = idx >> 4;
        int nv = idx & 15;
        int row = max(0, min(LL - 1, r0 + j));
        float4 v = *reinterpret_cast<const float4*>(&x[((size_t)b * LL + row) * NN + nv * 4]);
        *reinterpret_cast<float4*>(&xr[j * XR_STRIDE + nv * 4]) = v;
    }

    // ---- A fragments (wp, bf16 from global; k = lg*8+reg; lg>=2 -> zero) ----
    short8_t afrag[4];
    float4_t acc[4][4];   // [n-strip s][d-tile i]
    const short8_t zero8 = {0, 0, 0, 0, 0, 0, 0, 0};
#pragma unroll
    for (int i = 0; i < 4; ++i) {
        const int d = w * 64 + i * 16 + lr;
        short8_t v = *reinterpret_cast<const short8_t*>(&wp16[d * 16 + (lg & 1) * 8]);
        afrag[i] = (lg < 2) ? v : zero8;
        // bias for this thread's 4 consecutive d's: d = w*64 + i*16 + lg*4 + j
        float4 bv = *reinterpret_cast<const float4*>(&wp_b[w * 64 + i * 16 + lg * 4]);
        float4_t c4 = {bv.x, bv.y, bv.z, bv.w};
#pragma unroll
        for (int s = 0; s < 4; ++s) acc[s][i] = c4;
    }
    __syncthreads();

    // ---- build samp (fp32 bilinear) -> bf16 pairs into sampA[n][p] ----
    {
        const int pp  = t & 7;    // p-pair index: p = 2*pp, 2*pp+1
        const int nr0 = t >> 3;   // 0..31
        float f_[2]; int j0_[2], j1_[2];
#pragma unroll
        for (int q = 0; q < 2; ++q) {
            int p = pp * 2 + q;
            float xs = base + (float)p;
            xs = fminf(fmaxf(xs, 0.f), (float)(LL - 1));
            int i0 = (int)floorf(xs);
            f_[q]  = xs - (float)i0;
            j0_[q] = i0 - r0;                    // in [0, 16]
            j1_[q] = min(i0 + 1, LL - 1) - r0;   // in [0, 16]
        }
#pragma unroll
        for (int h = 0; h < 2; ++h) {
            int n = nr0 + 32 * h;
            unsigned pk = 0;
#pragma unroll
            for (int q = 0; q < 2; ++q) {
                float g0 = xr[j0_[q] * XR_STRIDE + n];
                float g1 = xr[j1_[q] * XR_STRIDE + n];
                float s  = g0 + f_[q] * (g1 - g0);
                pk |= f2bf(s) << (16 * q);
            }
            *reinterpret_cast<unsigned*>(&sampA[n * SA_ST + pp * 2]) = pk;
        }
    }
    __syncthreads();

    // ---- B fragments (samp): col = lr (n), k = lg*8+reg (lg>=2 x0 = junk ok) ----
    short8_t bfrag[4];
#pragma unroll
    for (int s = 0; s < 4; ++s)
        bfrag[s] = *reinterpret_cast<const short8_t*>(
            &sampA[(s * 16 + lr) * SA_ST + (lg & 1) * 8]);

    // ---- 16 MFMAs: acc[s][i] += wp_tile(i) x samp_strip(s) ----
#pragma unroll
    for (int s = 0; s < 4; ++s)
#pragma unroll
        for (int i = 0; i < 4; ++i)
            acc[s][i] = __builtin_amdgcn_mfma_f32_16x16x32_bf16(
                afrag[i], bfrag[s], acc[s][i], 0, 0, 0);

    // ---- wave-local epilogue: C slice [n=16][d=64] through private LDS,
    //      then 256B-contiguous nontemporal dwordx4 stores.
    //      Write banks: 4*(lr+lg+4i) mod 32 -> 8 lanes per 4-bank cluster
    //      (balanced, conflict-free). Read banks likewise.            ----
    float* cw = &cst[w * 16 * CW_ST];
    const int rowSel = lane >> 4;   // 0..3
    const int dq     = lane & 15;   // 16B chunk within wave's 256B slice
#pragma unroll
    for (int s = 0; s < 4; ++s) {
        // scatter: row = lr (strip-local n), words i*16+lg*4 .. +3
#pragma unroll
        for (int i = 0; i < 4; ++i)
            *reinterpret_cast<float4_t*>(&cw[lr * CW_ST + i * 16 + lg * 4]) = acc[s][i];
        // gather+store: 4 iters x 4 rows; each instr: 4 x 256B contiguous
#pragma unroll
        for (int it = 0; it < 4; ++it) {
            const int nl = it * 4 + rowSel;          // strip-local n
            float4_t v = *reinterpret_cast<const float4_t*>(&cw[nl * CW_ST + dq * 4]);
            const size_t rb = (((size_t)b * NN + s * 16 + nl) * AA + a) * DD
                              + w * 64 + dq * 4;
            __builtin_nontemporal_store(v, reinterpret_cast<float4_t*>(&out[rb]));
        }
    }
}

// ---------------------------------------------------------------------------
extern "C" void kernel_launch(void* const* d_in, const int* in_sizes, int n_in,
                              void* d_out, int out_size, void* d_ws, size_t ws_size,
                              hipStream_t stream)
{
    const float* x      = (const float*)d_in[0];
    const float* conv_w = (const float*)d_in[1];
    const float* conv_b = (const float*)d_in[2];
    const float* lin_w  = (const float*)d_in[3];
    const float* lin_b  = (const float*)d_in[4];
    const float* wp_w   = (const float*)d_in[5];
    const float* wp_b   = (const float*)d_in[6];
    float* out = (float*)d_out;

    float* pool_partial = (float*)d_ws;                       // 16384 floats
    float* delta        = pool_partial + 16384;               //  4096 floats
    unsigned short* wp16 = (unsigned short*)(delta + 4096);   //  4096 bf16

    conv_pool_kernel<<<dim3(8, BB), 256, 0, stream>>>(x, conv_w, conv_b, pool_partial);
    delta_kernel<<<BB, 64, 0, stream>>>(pool_partial, lin_w, lin_b, delta);

    // convert wp_w to bf16 once (tiny, 1 block) -- reuses delta_kernel's slot
    // in ws; done inline here to keep delta_kernel unchanged:
    // (wp16 conversion folded into patch via a tiny dedicated kernel)
    struct Cvt {
        static __global__ void run(const float* __restrict__ w4,
                                   unsigned short* __restrict__ o) {
            int i = blockIdx.x * 256 + threadIdx.x;   // 4096 elems
            float v = w4[i];
            union { float f; unsigned u; } c; c.f = v;
            o[i] = (unsigned short)((c.u + 0x7FFFu + ((c.u >> 16) & 1u)) >> 16);
        }
    };
    Cvt::run<<<16, 256, 0, stream>>>(wp_w, wp16);

    patch_proj_kernel<<<dim3(AA, BB), 256, 0, stream>>>(x, wp16, wp_b, delta, out);
}